// Round 8
// baseline (47.497 us; speedup 1.0000x reference)
//
#include <hip/hip_runtime.h>

#define ALPHA 0.2f
#define BATCH 16
#define WIN 100
#define KN 128          // nodes
#define DE 200          // embed dim
#define IT 8            // i-tile per k_attn block

typedef float v2f __attribute__((ext_vector_type(2)));

// Kernel A: grid 16b x 25dt, 1024 thr.
// thread (j, dh<4, wh<2): d-pair = dt*8+dh*2, w in [wh*50, wh*50+50).
// 50-deep x chain fully unrolled (25) -> ~2 latency rounds; partials via LDS.
__global__ __launch_bounds__(1024) void k_lin(
    const float* __restrict__ in, const float* __restrict__ lw,
    const float* __restrict__ lb, float* __restrict__ Rt, float* __restrict__ Lt) {
  int blk = blockIdx.x;
  int b = blk / 25, dt = blk % 25;
  int t = threadIdx.x;
  int j = t & (KN - 1);
  int g = t >> 7;                       // 0..7 (wave-pair uniform)
  int dh = g & 3, wh = g >> 2;
  int dp = __builtin_amdgcn_readfirstlane(dt * 8 + dh * 2);
  __shared__ float pl[2][8][KN];
  __shared__ float pr[2][8][KN];

  const float* xp = in + ((size_t)b * WIN + wh * 50) * KN + j;
  const float* lwl = lw + (size_t)(wh * 50) * DE + dp;
  const float* lwr = lw + (size_t)(WIN + wh * 50) * DE + dp;
  float la0 = 0, la1 = 0, ra0 = 0, ra1 = 0;
#pragma unroll 25
  for (int k = 0; k < 50; ++k) {
    float x = xp[(size_t)k * KN];
    float2 wl = *reinterpret_cast<const float2*>(lwl + (size_t)k * DE);
    float2 wr = *reinterpret_cast<const float2*>(lwr + (size_t)k * DE);
    la0 = fmaf(x, wl.x, la0); la1 = fmaf(x, wl.y, la1);
    ra0 = fmaf(x, wr.x, ra0); ra1 = fmaf(x, wr.y, ra1);
  }
  pl[wh][dh * 2][j] = la0; pl[wh][dh * 2 + 1][j] = la1;
  pr[wh][dh * 2][j] = ra0; pr[wh][dh * 2 + 1][j] = ra1;
  __syncthreads();

  int d8 = t >> 7;                      // 0..7
  int d = dt * 8 + d8;
  float lsum = pl[0][d8][j] + pl[1][d8][j];
  float rsum = pr[0][d8][j] + pr[1][d8][j] + lb[d];
  Lt[((size_t)b * DE + d) * KN + j] = lsum;
  Rt[((size_t)b * DE + d) * KN + j] = rsum;
}

// Kernel B: per (b, 8-i tile), 1024 thr (j x 8 d-slices of 25 d each).
//   M[ii][j] = sum_d min(Lt[d][i0+ii]+Rt[d][j],0)*aw[d]; ra[j] = sum_d Rt*aw
//   e = ra - 0.8*M (j-invariant per-i shift dropped; softmax unchanged)
//   wave-per-row softmax; PV reads x rows from global; sigmoid; store.
__global__ __launch_bounds__(1024) void k_attn_out(
    const float* __restrict__ in, const float* __restrict__ aw,
    const float* __restrict__ Rt, const float* __restrict__ Lt,
    float* __restrict__ out) {
  int blk = blockIdx.x;
  int b = blk >> 4, it = blk & 15;
  int i0 = it * IT;
  int t = threadIdx.x;
  __shared__ float part[8][IT][KN];
  __shared__ float part_r[8][KN];
  __shared__ float ats[IT][132];

  // e-phase: thread (j, dh) covers 25 d's for 8 i's; all 25 loads in flight
  {
    int j = t & (KN - 1);
    int dh = t >> 7;
    int db = __builtin_amdgcn_readfirstlane(dh * 25);
    const float* rtb = Rt + (size_t)b * DE * KN + j;
    const float* ltb = Lt + (size_t)b * DE * KN + i0;   // lane-invariant -> s_load
    v2f acc0 = 0.f, acc1 = 0.f, acc2 = 0.f, acc3 = 0.f;
    float racc = 0.f;
#pragma unroll 25
    for (int dd = 0; dd < 25; ++dd) {
      int d = db + dd;
      float r = rtb[(size_t)d * KN];
      float a = aw[d];
      float4 L0 = *reinterpret_cast<const float4*>(ltb + (size_t)d * KN);
      float4 L1 = *reinterpret_cast<const float4*>(ltb + (size_t)d * KN + 4);
      racc = fmaf(r, a, racc);
      v2f rv = {r, r}, av = {a, a}, z = 0.f;
      v2f p0 = (v2f){L0.x, L0.y} + rv;
      v2f p1 = (v2f){L0.z, L0.w} + rv;
      v2f p2 = (v2f){L1.x, L1.y} + rv;
      v2f p3 = (v2f){L1.z, L1.w} + rv;
      p0 = __builtin_elementwise_min(p0, z);
      p1 = __builtin_elementwise_min(p1, z);
      p2 = __builtin_elementwise_min(p2, z);
      p3 = __builtin_elementwise_min(p3, z);
      acc0 += p0 * av; acc1 += p1 * av; acc2 += p2 * av; acc3 += p3 * av;
    }
    part[dh][0][j] = acc0.x; part[dh][1][j] = acc0.y;
    part[dh][2][j] = acc1.x; part[dh][3][j] = acc1.y;
    part[dh][4][j] = acc2.x; part[dh][5][j] = acc2.y;
    part[dh][6][j] = acc3.x; part[dh][7][j] = acc3.y;
    part_r[dh][j] = racc;
  }
  __syncthreads();

  // softmax: wave r (r<8) owns row r; lanes l and l+64
  {
    int wid = t >> 6;
    if (wid < IT) {
      int r = wid, l = t & 63;
      float ra0 = 0.f, ra1 = 0.f, m0 = 0.f, m1 = 0.f;
#pragma unroll
      for (int dh = 0; dh < 8; ++dh) {
        ra0 += part_r[dh][l];     ra1 += part_r[dh][l + 64];
        m0  += part[dh][r][l];    m1  += part[dh][r][l + 64];
      }
      float e0 = fmaf(m0, -(1.f - ALPHA), ra0);
      float e1 = fmaf(m1, -(1.f - ALPHA), ra1);
      float m = fmaxf(e0, e1);
      for (int off = 32; off; off >>= 1) m = fmaxf(m, __shfl_xor(m, off));
      float p0 = __expf(e0 - m), p1 = __expf(e1 - m);
      float s = p0 + p1;
      for (int off = 32; off; off >>= 1) s += __shfl_xor(s, off);
      float inv = 1.f / s;
      ats[r][l] = p0 * inv;
      ats[r][l + 64] = p1 * inv;
    }
  }
  __syncthreads();

  // PV: thread (w, q<8): out[b][w][i0+q]; x rows from global (L1-shared x8)
  if (t < 8 * WIN) {
    int w = t >> 3, q = t & 7;
    const float* xw = in + ((size_t)b * WIN + w) * KN;
    const float* ap = &ats[q][0];
    float s = 0.f;
#pragma unroll 8
    for (int jj = 0; jj < KN; jj += 4) {
      float4 x4 = *reinterpret_cast<const float4*>(xw + jj);
      float4 aa = *reinterpret_cast<const float4*>(ap + jj);
      s = fmaf(aa.x, x4.x, s); s = fmaf(aa.y, x4.y, s);
      s = fmaf(aa.z, x4.z, s); s = fmaf(aa.w, x4.w, s);
    }
    out[((size_t)b * WIN + w) * KN + i0 + q] = 1.f / (1.f + __expf(-s));
  }
}

extern "C" void kernel_launch(void* const* d_in, const int* in_sizes, int n_in,
                              void* d_out, int out_size, void* d_ws, size_t ws_size,
                              hipStream_t stream) {
  const float* in = (const float*)d_in[0];   // (16,100,128)
  const float* lw = (const float*)d_in[1];   // (200,200)
  const float* lb = (const float*)d_in[2];   // (200,)
  const float* aw = (const float*)d_in[3];   // (200,)
  float* out = (float*)d_out;                // (16,100,128)

  float* Rt = (float*)d_ws;                          // 16*200*128 floats (1.6 MB)
  float* Lt = Rt + (size_t)BATCH * DE * KN;          // 16*200*128 floats (1.6 MB)

  k_lin     <<<BATCH * 25, 1024, 0, stream>>>(in, lw, lb, Rt, Lt);
  k_attn_out<<<BATCH * 16, 1024, 0, stream>>>(in, aw, Rt, Lt, out);
}

// Round 9
// 30.012 us; speedup vs baseline: 1.5826x; 1.5826x over previous
//
#include <hip/hip_runtime.h>

#define ALPHA 0.2f
#define BATCH 16
#define WIN 100
#define KN 128          // nodes
#define DE 200          // embed dim
#define IT 4            // i-tile per k_attn block

typedef float v2f __attribute__((ext_vector_type(2)));

// Kernel A: grid 16b x 50dt, 256 thr, zero LDS.
// lane j = t&127, d-pair = dt*4 + (t>>7)*2 (scalar path via readfirstlane).
//   Rt[b][d][j] = sum_w x[w][j]*lw[100+w][d] + lb[d]
//   Lt[b][d][j] = sum_w x[w][j]*lw[w][d]
__global__ __launch_bounds__(256) void k_lin(
    const float* __restrict__ in, const float* __restrict__ lw,
    const float* __restrict__ lb, float* __restrict__ Rt, float* __restrict__ Lt) {
  int blk = blockIdx.x;
  int b = blk / 50, dt = blk % 50;
  int t = threadIdx.x;
  int j = t & (KN - 1);
  int dbase = __builtin_amdgcn_readfirstlane(dt * 4 + (t >> 7) * 2);
  const float* inb = in + (size_t)b * WIN * KN + j;
  const float* lwl = lw + dbase;
  const float* lwr = lw + WIN * DE + dbase;
  float la0 = 0, la1 = 0, ra0 = 0, ra1 = 0;
#pragma unroll 10
  for (int w = 0; w < WIN; ++w) {
    float x = inb[w * KN];
    float2 wl = *reinterpret_cast<const float2*>(lwl + w * DE);
    float2 wr = *reinterpret_cast<const float2*>(lwr + w * DE);
    la0 = fmaf(x, wl.x, la0); la1 = fmaf(x, wl.y, la1);
    ra0 = fmaf(x, wr.x, ra0); ra1 = fmaf(x, wr.y, ra1);
  }
  float2 bb = *reinterpret_cast<const float2*>(lb + dbase);
  float* rp = Rt + ((size_t)b * DE + dbase) * KN + j;
  float* lp = Lt + ((size_t)b * DE + dbase) * KN + j;
  rp[0 * KN] = ra0 + bb.x; rp[1 * KN] = ra1 + bb.y;
  lp[0 * KN] = la0; lp[1 * KN] = la1;
}

// Kernel B: per (b, 4-i tile), 1024 thr (j x 8 d-slices of 25 d each).
//   M[ii][j] = sum_d min(Lt[d][i0+ii]+Rt[d][j],0)*aw[d]; ra[j] = sum_d Rt*aw
//   e = ra - 0.8*M (j-invariant per-i shift dropped; softmax unchanged)
//   wave-per-row softmax; PV reads x rows from global; sigmoid; store.
__global__ __launch_bounds__(1024) void k_attn_out(
    const float* __restrict__ in, const float* __restrict__ aw,
    const float* __restrict__ Rt, const float* __restrict__ Lt,
    float* __restrict__ out) {
  int blk = blockIdx.x;
  int b = blk >> 5, it = blk & 31;
  int i0 = it * IT;
  int t = threadIdx.x;
  __shared__ float part[8][IT][KN];
  __shared__ float part_r[8][KN];
  __shared__ float ats[IT][132];

  // e-phase: thread (j, dh) covers 25 d's for 4 i's (round-7 proven, unroll 5)
  {
    int j = t & (KN - 1);
    int dh = t >> 7;
    int db = __builtin_amdgcn_readfirstlane(dh * 25);
    const float* rtb = Rt + (size_t)b * DE * KN + j;
    const float* ltb = Lt + (size_t)b * DE * KN + i0;   // lane-invariant -> s_load
    v2f acc0 = 0.f, acc1 = 0.f;
    float racc = 0.f;
#pragma unroll 5
    for (int dd = 0; dd < 25; ++dd) {
      int d = db + dd;
      float r = rtb[(size_t)d * KN];
      float a = aw[d];
      float4 L0 = *reinterpret_cast<const float4*>(ltb + (size_t)d * KN);
      racc = fmaf(r, a, racc);
      v2f rv = {r, r}, av = {a, a}, z = 0.f;
      v2f p0 = (v2f){L0.x, L0.y} + rv;
      v2f p1 = (v2f){L0.z, L0.w} + rv;
      p0 = __builtin_elementwise_min(p0, z);
      p1 = __builtin_elementwise_min(p1, z);
      acc0 += p0 * av; acc1 += p1 * av;
    }
    part[dh][0][j] = acc0.x; part[dh][1][j] = acc0.y;
    part[dh][2][j] = acc1.x; part[dh][3][j] = acc1.y;
    part_r[dh][j] = racc;
  }
  __syncthreads();

  // softmax: wave r (r<4) owns row r; lanes l and l+64
  {
    int wid = t >> 6;
    if (wid < IT) {
      int r = wid, l = t & 63;
      float ra0 = 0.f, ra1 = 0.f, m0 = 0.f, m1 = 0.f;
#pragma unroll
      for (int dh = 0; dh < 8; ++dh) {
        ra0 += part_r[dh][l];     ra1 += part_r[dh][l + 64];
        m0  += part[dh][r][l];    m1  += part[dh][r][l + 64];
      }
      float e0 = fmaf(m0, -(1.f - ALPHA), ra0);
      float e1 = fmaf(m1, -(1.f - ALPHA), ra1);
      float m = fmaxf(e0, e1);
      for (int off = 32; off; off >>= 1) m = fmaxf(m, __shfl_xor(m, off));
      float p0 = __expf(e0 - m), p1 = __expf(e1 - m);
      float s = p0 + p1;
      for (int off = 32; off; off >>= 1) s += __shfl_xor(s, off);
      float inv = 1.f / s;
      ats[r][l] = p0 * inv;
      ats[r][l + 64] = p1 * inv;
    }
  }
  __syncthreads();

  // PV: thread (w, q<4): out[b][w][i0+q]; x rows from global (L1-shared x4)
  if (t < 4 * WIN) {
    int w = t >> 2, q = t & 3;
    const float* xw = in + ((size_t)b * WIN + w) * KN;
    const float* ap = &ats[q][0];
    float s = 0.f;
#pragma unroll 8
    for (int jj = 0; jj < KN; jj += 4) {
      float4 x4 = *reinterpret_cast<const float4*>(xw + jj);
      float4 aa = *reinterpret_cast<const float4*>(ap + jj);
      s = fmaf(aa.x, x4.x, s); s = fmaf(aa.y, x4.y, s);
      s = fmaf(aa.z, x4.z, s); s = fmaf(aa.w, x4.w, s);
    }
    out[((size_t)b * WIN + w) * KN + i0 + q] = 1.f / (1.f + __expf(-s));
  }
}

extern "C" void kernel_launch(void* const* d_in, const int* in_sizes, int n_in,
                              void* d_out, int out_size, void* d_ws, size_t ws_size,
                              hipStream_t stream) {
  const float* in = (const float*)d_in[0];   // (16,100,128)
  const float* lw = (const float*)d_in[1];   // (200,200)
  const float* lb = (const float*)d_in[2];   // (200,)
  const float* aw = (const float*)d_in[3];   // (200,)
  float* out = (float*)d_out;                // (16,100,128)

  float* Rt = (float*)d_ws;                          // 16*200*128 floats (1.6 MB)
  float* Lt = Rt + (size_t)BATCH * DE * KN;          // 16*200*128 floats (1.6 MB)

  k_lin     <<<BATCH * 50, 256, 0, stream>>>(in, lw, lb, Rt, Lt);
  k_attn_out<<<BATCH * 32, 1024, 0, stream>>>(in, aw, Rt, Lt, out);
}